// Round 2
// baseline (848.823 us; speedup 1.0000x reference)
//
#include <hip/hip_runtime.h>

#define NH 12
#define CHD 16
#define PQN 4
#define PVN 8
#define CSD 384
#define CZD 128
#define NN 512
#define HC 192
#define OUTD 2112
#define NSQ (NN*NN)

// ws layout (float offsets). a aliases b_pair (safe: same-lane read-then-write).
#define OFF_Q   0u
#define OFF_K   98304u
#define OFF_V   196608u
#define OFF_QP  294912u
#define OFF_KP  368640u
#define OFF_VP  442368u
#define OFF_A   589824u
#define OFF_CAT 3735552u
// total = 3735552 + 512*2112 = 4816896 floats = 19.3 MB

// ---------------- Kernel A: projections from s (4 rows/block) ----------------
#define RPB 4
__global__ __launch_bounds__(256) void k_proj(
    const float* __restrict__ s, const float* __restrict__ rot, const float* __restrict__ trans,
    const float* __restrict__ Wq, const float* __restrict__ bq,
    const float* __restrict__ Wkv, const float* __restrict__ bkv,
    const float* __restrict__ Wqp, const float* __restrict__ bqp,
    const float* __restrict__ Wkvp, const float* __restrict__ bkvp,
    float* __restrict__ ws)
{
  __shared__ float srow[RPB][CSD];
  __shared__ float praw[RPB][576];
  const int n0 = blockIdx.x*RPB, t = threadIdx.x;
  for (int idx = t; idx < RPB*CSD; idx += 256)
    srow[idx/CSD][idx%CSD] = s[(size_t)n0*CSD + idx];
  __syncthreads();
  for (int o = t; o < 1152; o += 256) {
    const float* W; int col, ld; float bias;
    if (o < 192)      { W = Wq;   col = o;     ld = 192; bias = bq[col];   }
    else if (o < 576) { W = Wkv;  col = o-192; ld = 384; bias = bkv[col];  }
    else if (o < 720) { W = Wqp;  col = o-576; ld = 144; bias = bqp[col];  }
    else              { W = Wkvp; col = o-720; ld = 432; bias = bkvp[col]; }
    float acc[RPB];
    #pragma unroll
    for (int r = 0; r < RPB; ++r) acc[r] = bias;
    #pragma unroll 4
    for (int c = 0; c < CSD; ++c) {
      float w = W[c*ld + col];
      #pragma unroll
      for (int r = 0; r < RPB; ++r) acc[r] += srow[r][c]*w;
    }
    #pragma unroll
    for (int r = 0; r < RPB; ++r) {
      int n = n0 + r;
      if (o < 192) {
        ws[OFF_Q + n*HC + col] = acc[r];
      } else if (o < 576) {
        int h = col >> 5, rr = col & 31;
        if (rr < CHD) ws[OFF_K + n*HC + h*CHD + rr] = acc[r];
        else          ws[OFF_V + n*HC + h*CHD + (rr-CHD)] = acc[r];
      } else if (o < 720) {
        praw[r][col] = acc[r];
      } else {
        praw[r][144 + col] = acc[r];
      }
    }
  }
  __syncthreads();
  // rotate + translate points: out[x] = sum_y R[x][y]*raw[y] + T[x]
  for (int m2 = t; m2 < RPB*192; m2 += 256) {
    int r = m2 / 192, m = m2 % 192;
    int n = n0 + r;
    float g0, g1, g2; float* dst;
    if (m < 48) {
      g0 = praw[r][m]; g1 = praw[r][48+m]; g2 = praw[r][96+m];
      int h = m >> 2, p = m & 3;
      dst = ws + OFF_QP + ((n*NH+h)*PQN + p)*3;
    } else {
      int mm = m - 48;                      // 0..143 over H*(PQ+PV)
      g0 = praw[r][144+mm]; g1 = praw[r][288+mm]; g2 = praw[r][432+mm];
      int h = mm / 12, pp = mm % 12;
      if (pp < PQN) dst = ws + OFF_KP + ((n*NH+h)*PQN + pp)*3;
      else          dst = ws + OFF_VP + ((n*NH+h)*PVN + (pp-PQN))*3;
    }
    #pragma unroll
    for (int x = 0; x < 3; ++x)
      dst[x] = rot[n*9+x*3+0]*g0 + rot[n*9+x*3+1]*g1 + rot[n*9+x*3+2]*g2 + trans[n*3+x];
  }
}

// ---------------- Kernel B: b_pair = sqrt(1/3)*(z @ Wb + bb), layout [h][i*N+j] ----------------
__global__ __launch_bounds__(256) void k_bpair(
    const float* __restrict__ z, const float* __restrict__ Wb, const float* __restrict__ bb,
    float* __restrict__ ws)
{
  __shared__ float wl[CZD*NH];
  const int t = threadIdx.x;
  for (int idx = t; idx < CZD*NH; idx += 256) wl[idx] = Wb[idx];
  __syncthreads();
  const int p = blockIdx.x*256 + t;          // pair index i*N+j
  float acc[NH];
  #pragma unroll
  for (int h = 0; h < NH; ++h) acc[h] = bb[h];
  const float4* zp = (const float4*)(z + (size_t)p*CZD);
  for (int cb = 0; cb < CZD/4; ++cb) {
    float4 u = zp[cb];
    float f[4] = { u.x, u.y, u.z, u.w };
    #pragma unroll
    for (int e = 0; e < 4; ++e) {
      const float* w = wl + (cb*4+e)*NH;
      #pragma unroll
      for (int h = 0; h < NH; ++h) acc[h] += f[e]*w[h];
    }
  }
  const float sc13 = 0.57735026918962576f;   // sqrt(1/3)
  #pragma unroll
  for (int h = 0; h < NH; ++h) ws[OFF_A + (size_t)h*NSQ + p] = acc[h]*sc13;
}

// ---------------- Kernel C: scores + softmax, one wave per (i,h); a aliases b_pair ----------------
__global__ __launch_bounds__(64) void k_attn(
    const float* __restrict__ mask, const float* __restrict__ head_w,
    float* __restrict__ ws)
{
  const int i = blockIdx.x, h = blockIdx.y, lane = threadIdx.x;
  const float* q = ws + OFF_Q + i*HC + h*CHD;
  float qv[CHD];
  #pragma unroll
  for (int c = 0; c < CHD; ++c) qv[c] = q[c];
  float qp[12];
  const float* qpp = ws + OFF_QP + (i*NH+h)*PQN*3;
  #pragma unroll
  for (int e = 0; e < 12; ++e) qp[e] = qpp[e];
  const float hw = log1pf(expf(head_w[h])) * 0.13608276348795434f; // softplus * sqrt(1/54)
  const float mi = mask[i];
  float sc[8];
  #pragma unroll
  for (int jj = 0; jj < 8; ++jj) {
    const int j = lane + jj*64;
    const float* kr = ws + OFF_K + j*HC + h*CHD;
    float dot = 0.f;
    #pragma unroll
    for (int c = 0; c < CHD; ++c) dot += qv[c]*kr[c];
    const float* kp = ws + OFF_KP + (j*NH+h)*PQN*3;
    float d2 = 0.f;
    #pragma unroll
    for (int e = 0; e < 12; ++e) { float d = qp[e]-kp[e]; d2 += d*d; }
    float b = ws[OFF_A + (size_t)h*NSQ + i*NN + j];   // pre-scaled b_pair
    sc[jj] = dot*0.14433756729740643f + b - 0.5f*hw*d2
           + 100000.0f*(mi*mask[j] - 1.0f);
  }
  float m = sc[0];
  #pragma unroll
  for (int jj = 1; jj < 8; ++jj) m = fmaxf(m, sc[jj]);
  for (int off = 32; off > 0; off >>= 1) m = fmaxf(m, __shfl_xor(m, off));
  float ssum = 0.f;
  #pragma unroll
  for (int jj = 0; jj < 8; ++jj) { sc[jj] = expf(sc[jj]-m); ssum += sc[jj]; }
  for (int off = 32; off > 0; off >>= 1) ssum += __shfl_xor(ssum, off);
  const float inv = 1.0f/ssum;
  #pragma unroll
  for (int jj = 0; jj < 8; ++jj)
    ws[OFF_A + (size_t)h*NSQ + i*NN + lane + jj*64] = sc[jj]*inv;
}

// ---------------- Kernel D: o_pair[i,h,c] = sum_j a[h,i,j]*z[i,j,c] -> cat[576..2111] ----------------
__global__ __launch_bounds__(256) void k_opair(
    const float* __restrict__ z, float* __restrict__ ws)
{
  __shared__ float al[NH][66];               // padded h-stride
  const int i = blockIdx.x, t = threadIdx.x;
  const int cg = t & 63, hg = t >> 6;        // c0 = 2*cg, heads hg*3..hg*3+2
  const int c0 = cg*2;
  float acc[3][2] = {{0.f,0.f},{0.f,0.f},{0.f,0.f}};
  for (int jb = 0; jb < NN; jb += 64) {
    __syncthreads();
    #pragma unroll
    for (int r = 0; r < 3; ++r) {
      int idx = t + r*256;                   // 768 = 12*64 values
      al[idx>>6][idx&63] = ws[OFF_A + (size_t)(idx>>6)*NSQ + i*NN + jb + (idx&63)];
    }
    __syncthreads();
    #pragma unroll 4
    for (int jj = 0; jj < 64; ++jj) {
      float2 zz = *(const float2*)(z + ((size_t)i*NN + jb + jj)*CZD + c0);
      #pragma unroll
      for (int e = 0; e < 3; ++e) {
        float av = al[hg*3+e][jj];
        acc[e][0] += av*zz.x;
        acc[e][1] += av*zz.y;
      }
    }
  }
  float* dst = ws + OFF_CAT + (size_t)i*OUTD + 576;
  #pragma unroll
  for (int e = 0; e < 3; ++e) {
    int h = hg*3+e;
    dst[h*CZD + c0]   = acc[e][0];
    dst[h*CZD + c0+1] = acc[e][1];
  }
}

// ---------------- Kernel E: o + o_pt (+ inverse rotation + norm) -> cat[0..575] ----------------
__global__ __launch_bounds__(512) void k_oacc(
    const float* __restrict__ rot, const float* __restrict__ trans,
    float* __restrict__ ws)
{
  __shared__ float al[2][NH][66];
  __shared__ float optl[2][288];
  const int i0 = blockIdx.x*2, t = threadIdx.x;
  float acc[2] = {0.f, 0.f};
  int hsel = 0;
  const float* src = ws;
  int off = 0, stride = 0;
  if (t < 192)      { hsel = t >> 4;      src = ws + OFF_V;  off = t;     stride = HC;  }
  else if (t < 480) { hsel = (t-192)/24;  src = ws + OFF_VP; off = t-192; stride = 288; }
  for (int jb = 0; jb < NN; jb += 64) {
    __syncthreads();
    for (int idx = t; idx < 2*NH*64; idx += 512) {
      int ii = idx / 768;
      int rem = idx - ii*768;
      al[ii][rem>>6][rem&63] = ws[OFF_A + (size_t)(rem>>6)*NSQ + (i0+ii)*NN + jb + (rem&63)];
    }
    __syncthreads();
    if (t < 480) {
      #pragma unroll 4
      for (int jj = 0; jj < 64; ++jj) {
        float val = src[(size_t)(jb+jj)*stride + off];
        acc[0] += al[0][hsel][jj]*val;
        acc[1] += al[1][hsel][jj]*val;
      }
    }
  }
  if (t < 192) {
    ws[OFF_CAT + (size_t)i0*OUTD + t]     = acc[0];
    ws[OFF_CAT + (size_t)(i0+1)*OUTD + t] = acc[1];
  } else if (t < 480) {
    optl[0][t-192] = acc[0];
    optl[1][t-192] = acc[1];
  }
  __syncthreads();
  if (t < 192) {
    int ii = t / 96, m = t - (t/96)*96;
    int h = m >> 3, p = m & 7;
    int n = i0 + ii;
    float g[3], Tl[3];
    #pragma unroll
    for (int y = 0; y < 3; ++y) { g[y] = optl[ii][h*24 + p*3 + y]; Tl[y] = trans[n*3+y]; }
    float nrm = 1e-8f;
    float loc[3];
    #pragma unroll
    for (int x = 0; x < 3; ++x) {
      float v = 0.f;
      #pragma unroll
      for (int y = 0; y < 3; ++y) v += rot[n*9 + y*3 + x] * (g[y]-Tl[y]);
      loc[x] = v; nrm += v*v;
    }
    nrm = sqrtf(nrm);
    float* crow = ws + OFF_CAT + (size_t)n*OUTD;
    crow[192 + 0*96 + m] = loc[0];
    crow[192 + 1*96 + m] = loc[1];
    crow[192 + 2*96 + m] = loc[2];
    crow[480 + m]        = nrm;
  }
}

// ---------------- Kernel F: out = cat @ Wout + bout (4 rows/block, f32 out) ----------------
__global__ __launch_bounds__(384) void k_out(
    const float* __restrict__ Wout, const float* __restrict__ bout,
    const float* __restrict__ ws, float* __restrict__ out)
{
  __shared__ float cl[4*OUTD];
  const int i0 = blockIdx.x*4, t = threadIdx.x;
  for (int idx = t; idx < 4*OUTD; idx += 384)
    cl[idx] = ws[OFF_CAT + (size_t)i0*OUTD + idx];
  __syncthreads();
  const int m = t;                            // 0..383
  float a0 = bout[m], a1 = a0, a2 = a0, a3 = a0;
  #pragma unroll 4
  for (int k = 0; k < OUTD; ++k) {
    float w = Wout[(size_t)k*CSD + m];
    a0 += cl[k]*w;
    a1 += cl[OUTD+k]*w;
    a2 += cl[2*OUTD+k]*w;
    a3 += cl[3*OUTD+k]*w;
  }
  out[(size_t)i0*CSD + m]     = a0;
  out[(size_t)(i0+1)*CSD + m] = a1;
  out[(size_t)(i0+2)*CSD + m] = a2;
  out[(size_t)(i0+3)*CSD + m] = a3;
}

extern "C" void kernel_launch(void* const* d_in, const int* in_sizes, int n_in,
                              void* d_out, int out_size, void* d_ws, size_t ws_size,
                              hipStream_t stream)
{
  const float* s     = (const float*)d_in[0];
  const float* z     = (const float*)d_in[1];
  const float* rot   = (const float*)d_in[2];
  const float* trans = (const float*)d_in[3];
  const float* mask  = (const float*)d_in[4];
  const float* Wq    = (const float*)d_in[5];
  const float* bq    = (const float*)d_in[6];
  const float* Wkv   = (const float*)d_in[7];
  const float* bkv   = (const float*)d_in[8];
  const float* Wqp   = (const float*)d_in[9];
  const float* bqp   = (const float*)d_in[10];
  const float* Wkvp  = (const float*)d_in[11];
  const float* bkvp  = (const float*)d_in[12];
  const float* Wb    = (const float*)d_in[13];
  const float* bb    = (const float*)d_in[14];
  const float* hwts  = (const float*)d_in[15];
  const float* Wout  = (const float*)d_in[16];
  const float* bout  = (const float*)d_in[17];
  float* ws  = (float*)d_ws;
  float* out = (float*)d_out;

  hipLaunchKernelGGL(k_proj,  dim3(NN/RPB),  dim3(256), 0, stream,
                     s, rot, trans, Wq, bq, Wkv, bkv, Wqp, bqp, Wkvp, bkvp, ws);
  hipLaunchKernelGGL(k_bpair, dim3(NSQ/256), dim3(256), 0, stream, z, Wb, bb, ws);
  hipLaunchKernelGGL(k_attn,  dim3(NN, NH),  dim3(64),  0, stream, mask, hwts, ws);
  hipLaunchKernelGGL(k_opair, dim3(NN),      dim3(256), 0, stream, z, ws);
  hipLaunchKernelGGL(k_oacc,  dim3(NN/2),    dim3(512), 0, stream, rot, trans, ws);
  hipLaunchKernelGGL(k_out,   dim3(NN/4),    dim3(384), 0, stream, Wout, bout, ws, out);
}

// Round 3
// 542.995 us; speedup vs baseline: 1.5632x; 1.5632x over previous
//
#include <hip/hip_runtime.h>
#include <hip/hip_bf16.h>

typedef __hip_bfloat16 bf16h;
typedef short bf16x8 __attribute__((ext_vector_type(8)));
typedef float f32x4 __attribute__((ext_vector_type(4)));

#define NH 12
#define CHD 16
#define PQN 4
#define PVN 8
#define CSD 384
#define CZD 128
#define NN 512
#define HC 192
#define OUTD 2112
#define NSQ (NN*NN)

// ws layout (float offsets). a aliases b_pair (safe: same-lane read-then-write).
#define OFF_Q   0u
#define OFF_K   98304u
#define OFF_V   196608u
#define OFF_QP  294912u
#define OFF_KP  368640u
#define OFF_VP  442368u
#define OFF_A   589824u
#define OFF_CAT 3735552u
// catb (bf16) lives at OFF_CAT: 512*2112*2B = 2.16MB; WoutT (bf16) right after.
// total bytes = 14942208 + 2162688 + 1622016 = 18.7 MB (within proven 19.3MB budget)

// ---------------- Kernel A: projections from s (4 rows/block) ----------------
#define RPB 4
__global__ __launch_bounds__(512) void k_proj(
    const float* __restrict__ s, const float* __restrict__ rot, const float* __restrict__ trans,
    const float* __restrict__ Wq, const float* __restrict__ bq,
    const float* __restrict__ Wkv, const float* __restrict__ bkv,
    const float* __restrict__ Wqp, const float* __restrict__ bqp,
    const float* __restrict__ Wkvp, const float* __restrict__ bkvp,
    float* __restrict__ ws)
{
  __shared__ float srow[RPB][CSD];
  __shared__ float praw[RPB][576];
  const int n0 = blockIdx.x*RPB, t = threadIdx.x;
  for (int idx = t; idx < RPB*CSD; idx += 512)
    srow[idx/CSD][idx%CSD] = s[(size_t)n0*CSD + idx];
  __syncthreads();
  for (int o = t; o < 1152; o += 512) {
    const float* W; int col, ld; float bias;
    if (o < 192)      { W = Wq;   col = o;     ld = 192; bias = bq[col];   }
    else if (o < 576) { W = Wkv;  col = o-192; ld = 384; bias = bkv[col];  }
    else if (o < 720) { W = Wqp;  col = o-576; ld = 144; bias = bqp[col];  }
    else              { W = Wkvp; col = o-720; ld = 432; bias = bkvp[col]; }
    float acc[RPB];
    #pragma unroll
    for (int r = 0; r < RPB; ++r) acc[r] = bias;
    #pragma unroll 4
    for (int c = 0; c < CSD; ++c) {
      float w = W[c*ld + col];
      #pragma unroll
      for (int r = 0; r < RPB; ++r) acc[r] += srow[r][c]*w;
    }
    #pragma unroll
    for (int r = 0; r < RPB; ++r) {
      int n = n0 + r;
      if (o < 192) {
        ws[OFF_Q + n*HC + col] = acc[r];
      } else if (o < 576) {
        int h = col >> 5, rr = col & 31;
        if (rr < CHD) ws[OFF_K + n*HC + h*CHD + rr] = acc[r];
        else          ws[OFF_V + n*HC + h*CHD + (rr-CHD)] = acc[r];
      } else if (o < 720) {
        praw[r][col] = acc[r];
      } else {
        praw[r][144 + col] = acc[r];
      }
    }
  }
  __syncthreads();
  // rotate + translate points: out[x] = sum_y R[x][y]*raw[y] + T[x]
  for (int m2 = t; m2 < RPB*192; m2 += 512) {
    int r = m2 / 192, m = m2 % 192;
    int n = n0 + r;
    float g0, g1, g2; float* dst;
    if (m < 48) {
      g0 = praw[r][m]; g1 = praw[r][48+m]; g2 = praw[r][96+m];
      int h = m >> 2, p = m & 3;
      dst = ws + OFF_QP + ((n*NH+h)*PQN + p)*3;
    } else {
      int mm = m - 48;                      // 0..143 over H*(PQ+PV)
      g0 = praw[r][144+mm]; g1 = praw[r][288+mm]; g2 = praw[r][432+mm];
      int h = mm / 12, pp = mm % 12;
      if (pp < PQN) dst = ws + OFF_KP + ((n*NH+h)*PQN + pp)*3;
      else          dst = ws + OFF_VP + ((n*NH+h)*PVN + (pp-PQN))*3;
    }
    #pragma unroll
    for (int x = 0; x < 3; ++x)
      dst[x] = rot[n*9+x*3+0]*g0 + rot[n*9+x*3+1]*g1 + rot[n*9+x*3+2]*g2 + trans[n*3+x];
  }
}

// ---------------- Kernel B: b_pair = sqrt(1/3)*(z @ Wb + bb), layout [h][i*N+j] ----------------
__global__ __launch_bounds__(256) void k_bpair(
    const float* __restrict__ z, const float* __restrict__ Wb, const float* __restrict__ bb,
    float* __restrict__ ws)
{
  __shared__ float wl[CZD*NH];
  const int t = threadIdx.x;
  for (int idx = t; idx < CZD*NH; idx += 256) wl[idx] = Wb[idx];
  __syncthreads();
  const int p = blockIdx.x*256 + t;          // pair index i*N+j
  float acc[NH];
  #pragma unroll
  for (int h = 0; h < NH; ++h) acc[h] = bb[h];
  const float4* zp = (const float4*)(z + (size_t)p*CZD);
  for (int cb = 0; cb < CZD/4; ++cb) {
    float4 u = zp[cb];
    float f[4] = { u.x, u.y, u.z, u.w };
    #pragma unroll
    for (int e = 0; e < 4; ++e) {
      const float* w = wl + (cb*4+e)*NH;
      #pragma unroll
      for (int h = 0; h < NH; ++h) acc[h] += f[e]*w[h];
    }
  }
  const float sc13 = 0.57735026918962576f;   // sqrt(1/3)
  #pragma unroll
  for (int h = 0; h < NH; ++h) ws[OFF_A + (size_t)h*NSQ + p] = acc[h]*sc13;
}

// ---------------- Kernel C: scores + softmax, one wave per (i,h); a aliases b_pair ----------------
__global__ __launch_bounds__(64) void k_attn(
    const float* __restrict__ mask, const float* __restrict__ head_w,
    float* __restrict__ ws)
{
  const int i = blockIdx.x, h = blockIdx.y, lane = threadIdx.x;
  const float* q = ws + OFF_Q + i*HC + h*CHD;
  float qv[CHD];
  #pragma unroll
  for (int c = 0; c < CHD; ++c) qv[c] = q[c];
  float qp[12];
  const float* qpp = ws + OFF_QP + (i*NH+h)*PQN*3;
  #pragma unroll
  for (int e = 0; e < 12; ++e) qp[e] = qpp[e];
  const float hw = log1pf(expf(head_w[h])) * 0.13608276348795434f; // softplus * sqrt(1/54)
  const float mi = mask[i];
  float sc[8];
  #pragma unroll
  for (int jj = 0; jj < 8; ++jj) {
    const int j = lane + jj*64;
    const float* kr = ws + OFF_K + j*HC + h*CHD;
    float dot = 0.f;
    #pragma unroll
    for (int c = 0; c < CHD; ++c) dot += qv[c]*kr[c];
    const float* kp = ws + OFF_KP + (j*NH+h)*PQN*3;
    float d2 = 0.f;
    #pragma unroll
    for (int e = 0; e < 12; ++e) { float d = qp[e]-kp[e]; d2 += d*d; }
    float b = ws[OFF_A + (size_t)h*NSQ + i*NN + j];   // pre-scaled b_pair
    sc[jj] = dot*0.14433756729740643f + b - 0.5f*hw*d2
           + 100000.0f*(mi*mask[j] - 1.0f);
  }
  float m = sc[0];
  #pragma unroll
  for (int jj = 1; jj < 8; ++jj) m = fmaxf(m, sc[jj]);
  for (int off = 32; off > 0; off >>= 1) m = fmaxf(m, __shfl_xor(m, off));
  float ssum = 0.f;
  #pragma unroll
  for (int jj = 0; jj < 8; ++jj) { sc[jj] = expf(sc[jj]-m); ssum += sc[jj]; }
  for (int off = 32; off > 0; off >>= 1) ssum += __shfl_xor(ssum, off);
  const float inv = 1.0f/ssum;
  #pragma unroll
  for (int jj = 0; jj < 8; ++jj)
    ws[OFF_A + (size_t)h*NSQ + i*NN + lane + jj*64] = sc[jj]*inv;
}

// ---------------- Kernel D: o_pair[i,h,c] = sum_j a[h,i,j]*z[i,j,c] -> catb[576..2111] (bf16) ----------------
__global__ __launch_bounds__(256) void k_opair(
    const float* __restrict__ z, float* __restrict__ ws)
{
  __shared__ float al[NH][66];               // padded h-stride
  const int i = blockIdx.x, t = threadIdx.x;
  const int cg = t & 63, hg = t >> 6;        // c0 = 2*cg, heads hg*3..hg*3+2
  const int c0 = cg*2;
  float acc[3][2] = {{0.f,0.f},{0.f,0.f},{0.f,0.f}};
  for (int jb = 0; jb < NN; jb += 64) {
    __syncthreads();
    #pragma unroll
    for (int r = 0; r < 3; ++r) {
      int idx = t + r*256;                   // 768 = 12*64 values
      al[idx>>6][idx&63] = ws[OFF_A + (size_t)(idx>>6)*NSQ + i*NN + jb + (idx&63)];
    }
    __syncthreads();
    #pragma unroll 4
    for (int jj = 0; jj < 64; ++jj) {
      float2 zz = *(const float2*)(z + ((size_t)i*NN + jb + jj)*CZD + c0);
      #pragma unroll
      for (int e = 0; e < 3; ++e) {
        float av = al[hg*3+e][jj];
        acc[e][0] += av*zz.x;
        acc[e][1] += av*zz.y;
      }
    }
  }
  bf16h* dst = (bf16h*)(ws + OFF_CAT) + (size_t)i*OUTD + 576;
  #pragma unroll
  for (int e = 0; e < 3; ++e) {
    int h = hg*3+e;
    dst[h*CZD + c0]   = __float2bfloat16(acc[e][0]);
    dst[h*CZD + c0+1] = __float2bfloat16(acc[e][1]);
  }
}

// ---------------- Kernel E: o + o_pt (+ inverse rotation + norm) -> catb[0..575] (bf16) ----------------
__global__ __launch_bounds__(512) void k_oacc(
    const float* __restrict__ rot, const float* __restrict__ trans,
    float* __restrict__ ws)
{
  __shared__ float al[2][NH][66];
  __shared__ float optl[2][288];
  const int i0 = blockIdx.x*2, t = threadIdx.x;
  float acc[2] = {0.f, 0.f};
  int hsel = 0;
  const float* src = ws;
  int off = 0, stride = 0;
  if (t < 192)      { hsel = t >> 4;      src = ws + OFF_V;  off = t;     stride = HC;  }
  else if (t < 480) { hsel = (t-192)/24;  src = ws + OFF_VP; off = t-192; stride = 288; }
  for (int jb = 0; jb < NN; jb += 64) {
    __syncthreads();
    for (int idx = t; idx < 2*NH*64; idx += 512) {
      int ii = idx / 768;
      int rem = idx - ii*768;
      al[ii][rem>>6][rem&63] = ws[OFF_A + (size_t)(rem>>6)*NSQ + (i0+ii)*NN + jb + (rem&63)];
    }
    __syncthreads();
    if (t < 480) {
      #pragma unroll 4
      for (int jj = 0; jj < 64; ++jj) {
        float val = src[(size_t)(jb+jj)*stride + off];
        acc[0] += al[0][hsel][jj]*val;
        acc[1] += al[1][hsel][jj]*val;
      }
    }
  }
  bf16h* catb = (bf16h*)(ws + OFF_CAT);
  if (t < 192) {
    catb[(size_t)i0*OUTD + t]     = __float2bfloat16(acc[0]);
    catb[(size_t)(i0+1)*OUTD + t] = __float2bfloat16(acc[1]);
  } else if (t < 480) {
    optl[0][t-192] = acc[0];
    optl[1][t-192] = acc[1];
  }
  __syncthreads();
  if (t < 192) {
    int ii = t / 96, m = t - (t/96)*96;
    int h = m >> 3, p = m & 7;
    int n = i0 + ii;
    float g[3], Tl[3];
    #pragma unroll
    for (int y = 0; y < 3; ++y) { g[y] = optl[ii][h*24 + p*3 + y]; Tl[y] = trans[n*3+y]; }
    float nrm = 1e-8f;
    float loc[3];
    #pragma unroll
    for (int x = 0; x < 3; ++x) {
      float v = 0.f;
      #pragma unroll
      for (int y = 0; y < 3; ++y) v += rot[n*9 + y*3 + x] * (g[y]-Tl[y]);
      loc[x] = v; nrm += v*v;
    }
    nrm = sqrtf(nrm);
    bf16h* crow = catb + (size_t)n*OUTD;
    crow[192 + 0*96 + m] = __float2bfloat16(loc[0]);
    crow[192 + 1*96 + m] = __float2bfloat16(loc[1]);
    crow[192 + 2*96 + m] = __float2bfloat16(loc[2]);
    crow[480 + m]        = __float2bfloat16(nrm);
  }
}

// ---------------- Kernel W: WoutT[n][k] = bf16(Wout[k][n]) ----------------
__global__ __launch_bounds__(256) void k_wconv(
    const float* __restrict__ Wout, float* __restrict__ ws)
{
  bf16h* woutT = (bf16h*)(ws + OFF_CAT) + (size_t)NN*OUTD;
  const int n = blockIdx.x;
  for (int k = threadIdx.x; k < OUTD; k += 256)
    woutT[(size_t)n*OUTD + k] = __float2bfloat16(Wout[(size_t)k*CSD + n]);
}

// ---------------- Kernel F: out = catb @ WoutT^T + bout via MFMA (m91-verified gemm_bt pattern) ----------------
__global__ __launch_bounds__(256) void k_out_mfma(
    const float* __restrict__ bout, const float* __restrict__ ws_c, float* __restrict__ out)
{
  const bf16h* catb  = (const bf16h*)(ws_c + OFF_CAT);
  const bf16h* woutT = catb + (size_t)NN*OUTD;
  const int t = threadIdx.x;
  const int wave = t >> 6, lane = t & 63;
  const int m0 = blockIdx.x*32 + (wave>>1)*16;
  const int n0 = blockIdx.y*32 + (wave&1)*16;
  const int lm = lane & 15, quad = lane >> 4;
  const bf16x8* pa = (const bf16x8*)(catb  + (size_t)(m0+lm)*OUTD) + quad;
  const bf16x8* pb = (const bf16x8*)(woutT + (size_t)(n0+lm)*OUTD) + quad;
  f32x4 acc = {0.f, 0.f, 0.f, 0.f};
  #pragma unroll 4
  for (int kk = 0; kk < OUTD/32; ++kk) {
    bf16x8 av = pa[kk*4];
    bf16x8 bv = pb[kk*4];
    acc = __builtin_amdgcn_mfma_f32_16x16x32_bf16(av, bv, acc, 0, 0, 0);
  }
  const int col = n0 + lm;
  const float bb = bout[col];
  #pragma unroll
  for (int r = 0; r < 4; ++r) {
    int row = m0 + quad*4 + r;
    out[(size_t)row*CSD + col] = acc[r] + bb;
  }
}

extern "C" void kernel_launch(void* const* d_in, const int* in_sizes, int n_in,
                              void* d_out, int out_size, void* d_ws, size_t ws_size,
                              hipStream_t stream)
{
  const float* s     = (const float*)d_in[0];
  const float* z     = (const float*)d_in[1];
  const float* rot   = (const float*)d_in[2];
  const float* trans = (const float*)d_in[3];
  const float* mask  = (const float*)d_in[4];
  const float* Wq    = (const float*)d_in[5];
  const float* bq    = (const float*)d_in[6];
  const float* Wkv   = (const float*)d_in[7];
  const float* bkv   = (const float*)d_in[8];
  const float* Wqp   = (const float*)d_in[9];
  const float* bqp   = (const float*)d_in[10];
  const float* Wkvp  = (const float*)d_in[11];
  const float* bkvp  = (const float*)d_in[12];
  const float* Wb    = (const float*)d_in[13];
  const float* bb    = (const float*)d_in[14];
  const float* hwts  = (const float*)d_in[15];
  const float* Wout  = (const float*)d_in[16];
  const float* bout  = (const float*)d_in[17];
  float* ws  = (float*)d_ws;
  float* out = (float*)d_out;

  hipLaunchKernelGGL(k_wconv, dim3(CSD),     dim3(256), 0, stream, Wout, ws);
  hipLaunchKernelGGL(k_proj,  dim3(NN/RPB),  dim3(512), 0, stream,
                     s, rot, trans, Wq, bq, Wkv, bkv, Wqp, bqp, Wkvp, bkvp, ws);
  hipLaunchKernelGGL(k_bpair, dim3(NSQ/256), dim3(256), 0, stream, z, Wb, bb, ws);
  hipLaunchKernelGGL(k_attn,  dim3(NN, NH),  dim3(64),  0, stream, mask, hwts, ws);
  hipLaunchKernelGGL(k_opair, dim3(NN),      dim3(256), 0, stream, z, ws);
  hipLaunchKernelGGL(k_oacc,  dim3(NN/2),    dim3(512), 0, stream, rot, trans, ws);
  hipLaunchKernelGGL(k_out_mfma, dim3(NN/32, CSD/32), dim3(256), 0, stream, bout, ws, out);
}

// Round 5
// 430.789 us; speedup vs baseline: 1.9704x; 1.2605x over previous
//
#include <hip/hip_runtime.h>
#include <hip/hip_bf16.h>

typedef __hip_bfloat16 bf16h;
typedef short bf16x8 __attribute__((ext_vector_type(8)));
typedef float f32x4 __attribute__((ext_vector_type(4)));

#define NH 12
#define CHD 16
#define PQN 4
#define PVN 8
#define CSD 384
#define CZD 128
#define NN 512
#define HC 192
#define OUTD 2112
#define NSQ (NN*NN)
#define NPROJ 1152

// ws layout (float offsets). a aliases b_pair (safe). RAW/SB/WCT live in the
// OFF_A region and are fully consumed by k_proj_epi BEFORE k_bpair writes a.
// SB is 512x384 bf16 = 98304 FLOATS (round-4 bug: was sized 49152 -> overlap).
#define OFF_Q    0u
#define OFF_K    98304u
#define OFF_V    196608u
#define OFF_QP   294912u
#define OFF_KP   368640u
#define OFF_VP   442368u
#define OFF_A    589824u
#define OFF_RAW  589824u     /* f32 512x1152 = 589824 floats -> ends 1179648 */
#define OFF_SB   1179648u    /* bf16 512x384  = 98304 floats -> ends 1277952 */
#define OFF_WCT  1277952u    /* bf16 1152x384 = 221184 floats -> ends 1499136 (< 3735552 OK) */
#define OFF_CATB 3735552u    /* bf16 512x2112 = 540672 floats */
#define OFF_WOT  4276224u    /* bf16 384x2112 = 405504 floats */
#define OFF_BCAT 4681728u    /* f32 1152 -> end 4682880 floats = 18.73 MB */

// ---------------- Kernel W1: pack weights/s to bf16, concat biases ----------------
__global__ __launch_bounds__(256) void k_wcat(
    const float* __restrict__ s,
    const float* __restrict__ Wq, const float* __restrict__ bq,
    const float* __restrict__ Wkv, const float* __restrict__ bkv,
    const float* __restrict__ Wqp, const float* __restrict__ bqp,
    const float* __restrict__ Wkvp, const float* __restrict__ bkvp,
    const float* __restrict__ Wout, float* __restrict__ ws)
{
  const int b = blockIdx.x, t = threadIdx.x;
  if (b < NPROJ) {
    const float* W; int col, ld;
    if (b < 192)      { W = Wq;   col = b;     ld = 192; }
    else if (b < 576) { W = Wkv;  col = b-192; ld = 384; }
    else if (b < 720) { W = Wqp;  col = b-576; ld = 144; }
    else              { W = Wkvp; col = b-720; ld = 432; }
    bf16h* dst = (bf16h*)(ws + OFF_WCT) + (size_t)b*CSD;
    for (int c = t; c < CSD; c += 256) dst[c] = __float2bfloat16(W[c*ld + col]);
  } else if (b < NPROJ + 128) {
    const int n0 = (b - NPROJ)*4;
    bf16h* sb = (bf16h*)(ws + OFF_SB);
    for (int idx = t; idx < 4*CSD; idx += 256)
      sb[(size_t)n0*CSD + idx] = __float2bfloat16(s[(size_t)n0*CSD + idx]);
  } else if (b < NPROJ + 128 + CSD) {
    // WoutT[n][k] = bf16(Wout[k][n])
    const int n = b - (NPROJ + 128);
    bf16h* woutT = (bf16h*)(ws + OFF_WOT);
    for (int k = t; k < OUTD; k += 256)
      woutT[(size_t)n*OUTD + k] = __float2bfloat16(Wout[(size_t)k*CSD + n]);
  } else {
    float* bcat = ws + OFF_BCAT;
    for (int o = t; o < NPROJ; o += 256) {
      float v;
      if (o < 192)      v = bq[o];
      else if (o < 576) v = bkv[o-192];
      else if (o < 720) v = bqp[o-576];
      else              v = bkvp[o-720];
      bcat[o] = v;
    }
  }
}

// ---------------- Kernel A1: raw = sb @ WcatT^T via MFMA ----------------
__global__ __launch_bounds__(256) void k_proj_gemm(float* __restrict__ ws)
{
  const bf16h* sb    = (const bf16h*)(ws + OFF_SB);
  const bf16h* wcatT = (const bf16h*)(ws + OFF_WCT);
  float* raw = ws + OFF_RAW;
  const int t = threadIdx.x;
  const int wave = t >> 6, lane = t & 63;
  const int m0 = blockIdx.x*32 + (wave>>1)*16;
  const int n0 = blockIdx.y*32 + (wave&1)*16;
  const int lm = lane & 15, quad = lane >> 4;
  const bf16x8* pa = (const bf16x8*)(sb    + (size_t)(m0+lm)*CSD) + quad;
  const bf16x8* pb = (const bf16x8*)(wcatT + (size_t)(n0+lm)*CSD) + quad;
  f32x4 acc = {0.f, 0.f, 0.f, 0.f};
  #pragma unroll
  for (int kk = 0; kk < CSD/32; ++kk) {
    bf16x8 av = pa[kk*4];
    bf16x8 bv = pb[kk*4];
    acc = __builtin_amdgcn_mfma_f32_16x16x32_bf16(av, bv, acc, 0, 0, 0);
  }
  const int col = n0 + lm;
  #pragma unroll
  for (int r = 0; r < 4; ++r) {
    int row = m0 + quad*4 + r;
    raw[(size_t)row*NPROJ + col] = acc[r];
  }
}

// ---------------- Kernel A2: bias + scatter + point rotation (4 rows/block) ----------------
#define RPB 4
__global__ __launch_bounds__(256) void k_proj_epi(
    const float* __restrict__ rot, const float* __restrict__ trans,
    float* __restrict__ ws)
{
  __shared__ float praw[RPB][576];
  const int n0 = blockIdx.x*RPB, t = threadIdx.x;
  const float* raw = ws + OFF_RAW;
  const float* bcat = ws + OFF_BCAT;
  for (int idx = t; idx < RPB*NPROJ; idx += 256) {
    int r = idx / NPROJ, o = idx - r*NPROJ;
    int n = n0 + r;
    float v = raw[(size_t)n*NPROJ + o] + bcat[o];
    if (o < 192) {
      ws[OFF_Q + n*HC + o] = v;
    } else if (o < 576) {
      int col = o-192, h = col >> 5, rr = col & 31;
      if (rr < CHD) ws[OFF_K + n*HC + h*CHD + rr] = v;
      else          ws[OFF_V + n*HC + h*CHD + (rr-CHD)] = v;
    } else {
      praw[r][o-576] = v;
    }
  }
  __syncthreads();
  for (int m2 = t; m2 < RPB*192; m2 += 256) {
    int r = m2 / 192, m = m2 % 192;
    int n = n0 + r;
    float g0, g1, g2; float* dst;
    if (m < 48) {
      g0 = praw[r][m]; g1 = praw[r][48+m]; g2 = praw[r][96+m];
      int h = m >> 2, p = m & 3;
      dst = ws + OFF_QP + ((n*NH+h)*PQN + p)*3;
    } else {
      int mm = m - 48;
      g0 = praw[r][144+mm]; g1 = praw[r][288+mm]; g2 = praw[r][432+mm];
      int h = mm / 12, pp = mm % 12;
      if (pp < PQN) dst = ws + OFF_KP + ((n*NH+h)*PQN + pp)*3;
      else          dst = ws + OFF_VP + ((n*NH+h)*PVN + (pp-PQN))*3;
    }
    #pragma unroll
    for (int x = 0; x < 3; ++x)
      dst[x] = rot[n*9+x*3+0]*g0 + rot[n*9+x*3+1]*g1 + rot[n*9+x*3+2]*g2 + trans[n*3+x];
  }
}

// ---------------- Kernel B: b_pair = sqrt(1/3)*(z @ Wb + bb), layout [h][i*N+j] ----------------
__global__ __launch_bounds__(256) void k_bpair(
    const float* __restrict__ z, const float* __restrict__ Wb, const float* __restrict__ bb,
    float* __restrict__ ws)
{
  __shared__ float wl[CZD*NH];
  const int t = threadIdx.x;
  for (int idx = t; idx < CZD*NH; idx += 256) wl[idx] = Wb[idx];
  __syncthreads();
  const int p = blockIdx.x*256 + t;          // pair index i*N+j
  float acc[NH];
  #pragma unroll
  for (int h = 0; h < NH; ++h) acc[h] = bb[h];
  const float4* zp = (const float4*)(z + (size_t)p*CZD);
  for (int cb = 0; cb < CZD/4; ++cb) {
    float4 u = zp[cb];
    float f[4] = { u.x, u.y, u.z, u.w };
    #pragma unroll
    for (int e = 0; e < 4; ++e) {
      const float* w = wl + (cb*4+e)*NH;
      #pragma unroll
      for (int h = 0; h < NH; ++h) acc[h] += f[e]*w[h];
    }
  }
  const float sc13 = 0.57735026918962576f;   // sqrt(1/3)
  #pragma unroll
  for (int h = 0; h < NH; ++h) ws[OFF_A + (size_t)h*NSQ + p] = acc[h]*sc13;
}

// ---------------- Kernel C: scores + softmax, one wave per (i,h); a aliases b_pair ----------------
__global__ __launch_bounds__(64) void k_attn(
    const float* __restrict__ mask, const float* __restrict__ head_w,
    float* __restrict__ ws)
{
  const int i = blockIdx.x, h = blockIdx.y, lane = threadIdx.x;
  const float* q = ws + OFF_Q + i*HC + h*CHD;
  float qv[CHD];
  #pragma unroll
  for (int c = 0; c < CHD; ++c) qv[c] = q[c];
  float qp[12];
  const float* qpp = ws + OFF_QP + (i*NH+h)*PQN*3;
  #pragma unroll
  for (int e = 0; e < 12; ++e) qp[e] = qpp[e];
  const float hw = log1pf(expf(head_w[h])) * 0.13608276348795434f; // softplus * sqrt(1/54)
  const float mi = mask[i];
  float sc[8];
  #pragma unroll
  for (int jj = 0; jj < 8; ++jj) {
    const int j = lane + jj*64;
    const float* kr = ws + OFF_K + j*HC + h*CHD;
    float dot = 0.f;
    #pragma unroll
    for (int c = 0; c < CHD; ++c) dot += qv[c]*kr[c];
    const float* kp = ws + OFF_KP + (j*NH+h)*PQN*3;
    float d2 = 0.f;
    #pragma unroll
    for (int e = 0; e < 12; ++e) { float d = qp[e]-kp[e]; d2 += d*d; }
    float b = ws[OFF_A + (size_t)h*NSQ + i*NN + j];   // pre-scaled b_pair
    sc[jj] = dot*0.14433756729740643f + b - 0.5f*hw*d2
           + 100000.0f*(mi*mask[j] - 1.0f);
  }
  float m = sc[0];
  #pragma unroll
  for (int jj = 1; jj < 8; ++jj) m = fmaxf(m, sc[jj]);
  for (int off = 32; off > 0; off >>= 1) m = fmaxf(m, __shfl_xor(m, off));
  float ssum = 0.f;
  #pragma unroll
  for (int jj = 0; jj < 8; ++jj) { sc[jj] = expf(sc[jj]-m); ssum += sc[jj]; }
  for (int off = 32; off > 0; off >>= 1) ssum += __shfl_xor(ssum, off);
  const float inv = 1.0f/ssum;
  #pragma unroll
  for (int jj = 0; jj < 8; ++jj)
    ws[OFF_A + (size_t)h*NSQ + i*NN + lane + jj*64] = sc[jj]*inv;
}

// ---------------- Kernel D: o_pair[i,h,c] = sum_j a[h,i,j]*z[i,j,c] -> catb (bf16) ----------------
__global__ __launch_bounds__(256) void k_opair(
    const float* __restrict__ z, float* __restrict__ ws)
{
  __shared__ float al[NH][66];               // padded h-stride
  const int i = blockIdx.x, t = threadIdx.x;
  const int cg = t & 63, hg = t >> 6;        // c0 = 2*cg, heads hg*3..hg*3+2
  const int c0 = cg*2;
  float acc[3][2] = {{0.f,0.f},{0.f,0.f},{0.f,0.f}};
  for (int jb = 0; jb < NN; jb += 64) {
    __syncthreads();
    #pragma unroll
    for (int r = 0; r < 3; ++r) {
      int idx = t + r*256;                   // 768 = 12*64 values
      al[idx>>6][idx&63] = ws[OFF_A + (size_t)(idx>>6)*NSQ + i*NN + jb + (idx&63)];
    }
    __syncthreads();
    #pragma unroll 4
    for (int jj = 0; jj < 64; ++jj) {
      float2 zz = *(const float2*)(z + ((size_t)i*NN + jb + jj)*CZD + c0);
      #pragma unroll
      for (int e = 0; e < 3; ++e) {
        float av = al[hg*3+e][jj];
        acc[e][0] += av*zz.x;
        acc[e][1] += av*zz.y;
      }
    }
  }
  bf16h* dst = (bf16h*)(ws + OFF_CATB) + (size_t)i*OUTD + 576;
  #pragma unroll
  for (int e = 0; e < 3; ++e) {
    int h = hg*3+e;
    dst[h*CZD + c0]   = __float2bfloat16(acc[e][0]);
    dst[h*CZD + c0+1] = __float2bfloat16(acc[e][1]);
  }
}

// ---------------- Kernel E: o + o_pt (+ inverse rotation + norm) -> catb (bf16) ----------------
__global__ __launch_bounds__(512) void k_oacc(
    const float* __restrict__ rot, const float* __restrict__ trans,
    float* __restrict__ ws)
{
  __shared__ float al[2][NH][66];
  __shared__ float optl[2][288];
  const int i0 = blockIdx.x*2, t = threadIdx.x;
  float acc[2] = {0.f, 0.f};
  int hsel = 0;
  const float* src = ws;
  int off = 0, stride = 0;
  if (t < 192)      { hsel = t >> 4;      src = ws + OFF_V;  off = t;     stride = HC;  }
  else if (t < 480) { hsel = (t-192)/24;  src = ws + OFF_VP; off = t-192; stride = 288; }
  for (int jb = 0; jb < NN; jb += 64) {
    __syncthreads();
    for (int idx = t; idx < 2*NH*64; idx += 512) {
      int ii = idx / 768;
      int rem = idx - ii*768;
      al[ii][rem>>6][rem&63] = ws[OFF_A + (size_t)(rem>>6)*NSQ + (i0+ii)*NN + jb + (rem&63)];
    }
    __syncthreads();
    if (t < 480) {
      #pragma unroll 4
      for (int jj = 0; jj < 64; ++jj) {
        float val = src[(size_t)(jb+jj)*stride + off];
        acc[0] += al[0][hsel][jj]*val;
        acc[1] += al[1][hsel][jj]*val;
      }
    }
  }
  bf16h* catb = (bf16h*)(ws + OFF_CATB);
  if (t < 192) {
    catb[(size_t)i0*OUTD + t]     = __float2bfloat16(acc[0]);
    catb[(size_t)(i0+1)*OUTD + t] = __float2bfloat16(acc[1]);
  } else if (t < 480) {
    optl[0][t-192] = acc[0];
    optl[1][t-192] = acc[1];
  }
  __syncthreads();
  if (t < 192) {
    int ii = t / 96, m = t - (t/96)*96;
    int h = m >> 3, p = m & 7;
    int n = i0 + ii;
    float g[3], Tl[3];
    #pragma unroll
    for (int y = 0; y < 3; ++y) { g[y] = optl[ii][h*24 + p*3 + y]; Tl[y] = trans[n*3+y]; }
    float nrm = 1e-8f;
    float loc[3];
    #pragma unroll
    for (int x = 0; x < 3; ++x) {
      float v = 0.f;
      #pragma unroll
      for (int y = 0; y < 3; ++y) v += rot[n*9 + y*3 + x] * (g[y]-Tl[y]);
      loc[x] = v; nrm += v*v;
    }
    nrm = sqrtf(nrm);
    bf16h* crow = catb + (size_t)n*OUTD;
    crow[192 + 0*96 + m] = __float2bfloat16(loc[0]);
    crow[192 + 1*96 + m] = __float2bfloat16(loc[1]);
    crow[192 + 2*96 + m] = __float2bfloat16(loc[2]);
    crow[480 + m]        = __float2bfloat16(nrm);
  }
}

// ---------------- Kernel F: out = catb @ WoutT^T + bout via MFMA ----------------
__global__ __launch_bounds__(256) void k_out_mfma(
    const float* __restrict__ bout, const float* __restrict__ ws_c, float* __restrict__ out)
{
  const bf16h* catb  = (const bf16h*)(ws_c + OFF_CATB);
  const bf16h* woutT = (const bf16h*)(ws_c + OFF_WOT);
  const int t = threadIdx.x;
  const int wave = t >> 6, lane = t & 63;
  const int m0 = blockIdx.x*32 + (wave>>1)*16;
  const int n0 = blockIdx.y*32 + (wave&1)*16;
  const int lm = lane & 15, quad = lane >> 4;
  const bf16x8* pa = (const bf16x8*)(catb  + (size_t)(m0+lm)*OUTD) + quad;
  const bf16x8* pb = (const bf16x8*)(woutT + (size_t)(n0+lm)*OUTD) + quad;
  f32x4 acc = {0.f, 0.f, 0.f, 0.f};
  #pragma unroll 4
  for (int kk = 0; kk < OUTD/32; ++kk) {
    bf16x8 av = pa[kk*4];
    bf16x8 bv = pb[kk*4];
    acc = __builtin_amdgcn_mfma_f32_16x16x32_bf16(av, bv, acc, 0, 0, 0);
  }
  const int col = n0 + lm;
  const float bb = bout[col];
  #pragma unroll
  for (int r = 0; r < 4; ++r) {
    int row = m0 + quad*4 + r;
    out[(size_t)row*CSD + col] = acc[r] + bb;
  }
}

extern "C" void kernel_launch(void* const* d_in, const int* in_sizes, int n_in,
                              void* d_out, int out_size, void* d_ws, size_t ws_size,
                              hipStream_t stream)
{
  const float* s     = (const float*)d_in[0];
  const float* z     = (const float*)d_in[1];
  const float* rot   = (const float*)d_in[2];
  const float* trans = (const float*)d_in[3];
  const float* mask  = (const float*)d_in[4];
  const float* Wq    = (const float*)d_in[5];
  const float* bq    = (const float*)d_in[6];
  const float* Wkv   = (const float*)d_in[7];
  const float* bkv   = (const float*)d_in[8];
  const float* Wqp   = (const float*)d_in[9];
  const float* bqp   = (const float*)d_in[10];
  const float* Wkvp  = (const float*)d_in[11];
  const float* bkvp  = (const float*)d_in[12];
  const float* Wb    = (const float*)d_in[13];
  const float* bb    = (const float*)d_in[14];
  const float* hwts  = (const float*)d_in[15];
  const float* Wout  = (const float*)d_in[16];
  const float* bout  = (const float*)d_in[17];
  float* ws  = (float*)d_ws;
  float* out = (float*)d_out;

  hipLaunchKernelGGL(k_wcat, dim3(NPROJ + 128 + CSD + 1), dim3(256), 0, stream,
                     s, Wq, bq, Wkv, bkv, Wqp, bqp, Wkvp, bkvp, Wout, ws);
  hipLaunchKernelGGL(k_proj_gemm, dim3(NN/32, NPROJ/32), dim3(256), 0, stream, ws);
  hipLaunchKernelGGL(k_proj_epi,  dim3(NN/RPB), dim3(256), 0, stream, rot, trans, ws);
  hipLaunchKernelGGL(k_bpair, dim3(NSQ/256), dim3(256), 0, stream, z, Wb, bb, ws);
  hipLaunchKernelGGL(k_attn,  dim3(NN, NH),  dim3(64),  0, stream, mask, hwts, ws);
  hipLaunchKernelGGL(k_opair, dim3(NN),      dim3(256), 0, stream, z, ws);
  hipLaunchKernelGGL(k_oacc,  dim3(NN/2),    dim3(512), 0, stream, rot, trans, ws);
  hipLaunchKernelGGL(k_out_mfma, dim3(NN/32, CSD/32), dim3(256), 0, stream, bout, ws, out);
}